// Round 1
// baseline (129.945 us; speedup 1.0000x reference)
//
#include <hip/hip_runtime.h>

#define NB 48
#define NH 512
#define NW 512
#define NK 33
#define HWSZ (NH * NW)

// ws layout (4-byte units): [0 .. 2*NB) int {ymin,xmin} per image;
// [96] float hann_sum; [97] int hann_nnz. d_out[0] zeroed by prep_kernel.

__global__ void __launch_bounds__(256) prep_kernel(
    const float* __restrict__ tgt, const float* __restrict__ hann,
    int* wsi, float* wsf, float* out) {
  const int b = blockIdx.x;
  const int tid = threadIdx.x;
  __shared__ int s_yh, s_xh, s_ymin, s_xmin, s_nnz;
  __shared__ float s_sum;
  if (tid == 0) { s_ymin = NH; s_xmin = NW; s_sum = 0.f; s_nnz = 0; }
  __syncthreads();
  const float* t = tgt + (size_t)b * HWSZ;
  // stride-33 lattice: exactly one sample lands inside the 33x33 square
  const int y = (tid >> 4) * NK;   // 0,33,...,495
  const int x = (tid & 15) * NK;
  if (t[y * NW + x] == 1.0f) { s_yh = y; s_xh = x; }
  __syncthreads();
  const int yh = s_yh, xh = s_xh;
  if (tid < NK) {
    int yy = yh - (NK - 1) + tid;
    if (yy >= 0 && t[yy * NW + xh] == 1.0f) atomicMin(&s_ymin, yy);
  } else if (tid >= 64 && tid < 64 + NK) {
    int xx = xh - (NK - 1) + (tid - 64);
    if (xx >= 0 && t[yh * NW + xx] == 1.0f) atomicMin(&s_xmin, xx);
  }
  if (b == 0) {  // hann stats (sum + nonzero count), computed once
    float lsum = 0.f; int lnnz = 0;
    for (int i = tid; i < NK * NK; i += 256) {
      float v = hann[i];
      lsum += v; lnnz += (v != 0.f);
    }
    atomicAdd(&s_sum, lsum);
    atomicAdd(&s_nnz, lnnz);
  }
  __syncthreads();
  if (tid == 0) {
    wsi[2 * b] = s_ymin;
    wsi[2 * b + 1] = s_xmin;
    if (b == 0) { wsf[96] = s_sum; wsi[97] = s_nnz; out[0] = 0.f; }
  }
}

__global__ void __launch_bounds__(256) loss_kernel(
    const float* __restrict__ pred, const float* __restrict__ hann,
    const int* wsi, const float* wsf, float* out) {
  const float S = wsf[96];
  const int nnz = wsi[97];
  const float scale = 1.0f / (float)NB;             // fold batch-mean in
  const float wpos_s = scale / (2.0f * S);          // hann / (2S) / B
  const float negw = scale / (2.0f * (float)(HWSZ - nnz));
  float acc = 0.f;
  const int N4 = NB * HWSZ / 4;
  const int stride = gridDim.x * blockDim.x;
  for (int i = blockIdx.x * blockDim.x + threadIdx.x; i < N4; i += stride) {
    const int pix = i << 2;
    const int b = pix >> 18;             // / (512*512)
    const int rem = pix & (HWSZ - 1);
    const int y = rem >> 9;              // / 512
    const int x = rem & (NW - 1);
    const int ymin = wsi[2 * b];
    const int xmin = wsi[2 * b + 1];
    const float4 p = reinterpret_cast<const float4*>(pred)[i];
    const int dy = y - ymin;
    const bool yin = (unsigned)dy < (unsigned)NK;
    const float pv[4] = {p.x, p.y, p.z, p.w};
#pragma unroll
    for (int j = 0; j < 4; ++j) {
      const float px = pv[j];
      float w = negw, tv = 0.f;
      const int dx = x + j - xmin;
      if (yin && (unsigned)dx < (unsigned)NK) {
        const float hv = hann[dy * NK + dx];
        if (hv != 0.f) w = hv * wpos_s;
        tv = 1.f;  // inside window == inside target square
      }
      // stable BCE-with-logits: max(x,0) + log(1+exp(-|x|)) - x*t
      const float bce =
          fmaxf(px, 0.f) + __logf(1.f + __expf(-fabsf(px))) - px * tv;
      acc = fmaf(w, bce, acc);
    }
  }
  // wave (64-lane) reduce, then block reduce, then one atomic per block
#pragma unroll
  for (int off = 32; off > 0; off >>= 1) acc += __shfl_down(acc, off);
  __shared__ float s_part[4];
  const int lane = threadIdx.x & 63, wid = threadIdx.x >> 6;
  if (lane == 0) s_part[wid] = acc;
  __syncthreads();
  if (threadIdx.x == 0) {
    atomicAdd(out, s_part[0] + s_part[1] + s_part[2] + s_part[3]);
  }
}

extern "C" void kernel_launch(void* const* d_in, const int* in_sizes, int n_in,
                              void* d_out, int out_size, void* d_ws, size_t ws_size,
                              hipStream_t stream) {
  const float* pred = (const float*)d_in[0];
  const float* tgt  = (const float*)d_in[1];
  const float* hann = (const float*)d_in[2];
  float* out = (float*)d_out;
  int* wsi = (int*)d_ws;
  float* wsf = (float*)d_ws;
  prep_kernel<<<NB, 256, 0, stream>>>(tgt, hann, wsi, wsf, out);
  loss_kernel<<<1024, 256, 0, stream>>>(pred, hann, wsi, wsf, out);
}

// Round 2
// 125.521 us; speedup vs baseline: 1.0352x; 1.0352x over previous
//
#include <hip/hip_runtime.h>

#define NB 48
#define NH 512
#define NW 512
#define NK 33
#define HWSZ (NH * NW)
#define SLICES 32                       // blocks per image
#define ROWS_PER_BLK (NH / SLICES)      // 16 rows
#define NBLK (NB * SLICES)              // 1536 blocks
#define ITERS (ROWS_PER_BLK * NW / 4 / 256)  // 8 float4-iters per thread

// Single fused kernel: each block (a) finds its image's 33x33 bbox via a
// stride-33 lattice probe (exactly one of the 16x16 lattice points lands in
// the square), (b) computes hann sum / nonzero count, (c) streams its
// 16-row slice of pred with fused weighted-BCE, (d) stores one partial.
__global__ void __launch_bounds__(256) fused_kernel(
    const float* __restrict__ pred, const float* __restrict__ tgt,
    const float* __restrict__ hann, float* __restrict__ partial) {
  const int tid = threadIdx.x;
  // image = blockIdx % 48: 48 % 8 == 0, so all blocks of one image share an
  // XCD -> the scattered probe lines are fetched once per image.
  const int b = blockIdx.x % NB;
  const int slice = blockIdx.x / NB;

  __shared__ int s_yh, s_xh, s_ymin, s_xmin;
  __shared__ float s_red[8];
  if (tid == 0) { s_ymin = NH; s_xmin = NW; }
  __syncthreads();

  const float* t = tgt + (size_t)b * HWSZ;
  {  // lattice probe: 33 consecutive ints contain exactly one multiple of 33
    const int y = (tid >> 4) * NK;   // 0,33,...,495
    const int x = (tid & 15) * NK;
    if (t[y * NW + x] == 1.0f) { s_yh = y; s_xh = x; }
  }
  // hann stats (overlaps the probe's memory latency)
  float hsum = 0.f, hnnz = 0.f;
  for (int i = tid; i < NK * NK; i += 256) {
    const float v = hann[i];
    hsum += v;
    hnnz += (v != 0.f) ? 1.f : 0.f;
  }
  __syncthreads();
  const int yh = s_yh, xh = s_xh;
  if (tid < NK) {
    const int yy = yh - (NK - 1) + tid;
    if (yy >= 0 && t[yy * NW + xh] == 1.0f) atomicMin(&s_ymin, yy);
  } else if (tid >= 64 && tid < 64 + NK) {
    const int xx = xh - (NK - 1) + (tid - 64);
    if (xx >= 0 && t[yh * NW + xx] == 1.0f) atomicMin(&s_xmin, xx);
  }
#pragma unroll
  for (int off = 32; off; off >>= 1) {
    hsum += __shfl_down(hsum, off);
    hnnz += __shfl_down(hnnz, off);
  }
  if ((tid & 63) == 0) { s_red[tid >> 6] = hsum; s_red[4 + (tid >> 6)] = hnnz; }
  __syncthreads();

  const int ymin = s_ymin, xmin = s_xmin;
  const float S = s_red[0] + s_red[1] + s_red[2] + s_red[3];
  const float nnz = s_red[4] + s_red[5] + s_red[6] + s_red[7];
  const float wpos_s = 1.0f / (2.0f * S * (float)NB);              // hann/(2S)/B
  const float negw = 1.0f / (2.0f * ((float)HWSZ - nnz) * (float)NB);

  // stream 16 rows of pred
  const int r0 = slice * ROWS_PER_BLK;
  const float4* p4 =
      reinterpret_cast<const float4*>(pred + (size_t)b * HWSZ + r0 * NW);
  float acc = 0.f;
#pragma unroll
  for (int it = 0; it < ITERS; ++it) {
    const int off = it * 256 + tid;        // float4 index within slice
    const int y = r0 + (off >> 7);         // 128 float4 per row
    const int x = (off & 127) << 2;
    const float4 pv = p4[off];
    const int dy = y - ymin;
    const bool yin = (unsigned)dy < (unsigned)NK;
    const float arr[4] = {pv.x, pv.y, pv.z, pv.w};
#pragma unroll
    for (int j = 0; j < 4; ++j) {
      const float px = arr[j];
      const int dx = x + j - xmin;
      float w = negw, tv = 0.f;
      if (yin && (unsigned)dx < (unsigned)NK) {
        const float hv = hann[dy * NK + dx];
        if (hv != 0.f) w = hv * wpos_s;
        tv = 1.f;  // inside window == inside target square
      }
      // stable BCE-with-logits: max(x,0) + log(1+exp(-|x|)) - x*t
      const float bce =
          fmaxf(px, 0.f) + __logf(1.f + __expf(-fabsf(px))) - px * tv;
      acc = fmaf(w, bce, acc);
    }
  }
#pragma unroll
  for (int off = 32; off; off >>= 1) acc += __shfl_down(acc, off);
  __syncthreads();
  if ((tid & 63) == 0) s_red[tid >> 6] = acc;
  __syncthreads();
  if (tid == 0)
    partial[blockIdx.x] = s_red[0] + s_red[1] + s_red[2] + s_red[3];
}

// Tiny epilogue: sum 1536 partials, plain store (no pre-zero of d_out needed).
__global__ void __launch_bounds__(256) reduce_kernel(
    const float* __restrict__ partial, float* __restrict__ out) {
  float a = 0.f;
  for (int i = threadIdx.x; i < NBLK; i += 256) a += partial[i];
#pragma unroll
  for (int off = 32; off; off >>= 1) a += __shfl_down(a, off);
  __shared__ float s[4];
  if ((threadIdx.x & 63) == 0) s[threadIdx.x >> 6] = a;
  __syncthreads();
  if (threadIdx.x == 0) out[0] = s[0] + s[1] + s[2] + s[3];
}

extern "C" void kernel_launch(void* const* d_in, const int* in_sizes, int n_in,
                              void* d_out, int out_size, void* d_ws, size_t ws_size,
                              hipStream_t stream) {
  const float* pred = (const float*)d_in[0];
  const float* tgt  = (const float*)d_in[1];
  const float* hann = (const float*)d_in[2];
  float* partial = (float*)d_ws;
  float* out = (float*)d_out;
  fused_kernel<<<NBLK, 256, 0, stream>>>(pred, tgt, hann, partial);
  reduce_kernel<<<1, 256, 0, stream>>>(partial, out);
}